// Round 13
// baseline (4904.040 us; speedup 1.0000x reference)
//
#include <hip/hip_runtime.h>
#include <hip/hip_bf16.h>

// Problem constants
#define BB 64     // batch
#define TT 512    // seq len
#define EE 512    // embed dim
#define HH 512    // hidden
#define G4 2048   // 4*H
#define VV 32000  // vocab
#define NWG 16    // workgroups in persistent recurrence kernel (32 units each)

typedef float f32x4 __attribute__((ext_vector_type(4)));
typedef short s16x8 __attribute__((ext_vector_type(8)));
typedef unsigned short u16x8 __attribute__((ext_vector_type(8)));

__device__ __forceinline__ unsigned short f2bf(float x) {
    __hip_bfloat16 h = __float2bfloat16(x);
    return *(unsigned short*)&h;
}
__device__ __forceinline__ float b2f(unsigned short u) {
    return __uint_as_float(((unsigned)u) << 16);
}

// ---------------- C0: fp32 -> bf16 flat convert (emb) ---------------------------
__global__ __launch_bounds__(256) void c_bf16(const float* __restrict__ in,
                                              unsigned short* __restrict__ out, int n4) {
    int i = blockIdx.x * 256 + threadIdx.x;
    if (i < n4) {
        float4 v = ((const float4*)in)[i];
        ushort4 o;
        o.x = f2bf(v.x); o.y = f2bf(v.y); o.z = f2bf(v.z); o.w = f2bf(v.w);
        ((ushort4*)out)[i] = o;
    }
}

// ---------------- C1: transpose+convert [512][2048] fp32 -> [2048][512] bf16 ----
__global__ __launch_bounds__(256) void c_wT(const float* __restrict__ in,
                                            unsigned short* __restrict__ out) {
    __shared__ float tile[32][33];
    int gx = blockIdx.x * 32;           // col dim (2048)
    int ky = blockIdx.y * 32;           // row dim (512)
    int tx = threadIdx.x & 31, ty = threadIdx.x >> 5;   // 32 x 8
    #pragma unroll
    for (int i = 0; i < 32; i += 8)
        tile[ty + i][tx] = in[(size_t)(ky + ty + i) * G4 + gx + tx];
    __syncthreads();
    #pragma unroll
    for (int i = 0; i < 32; i += 8)
        out[(size_t)(gx + ty + i) * HH + ky + tx] = f2bf(tile[tx][ty + i]);
}

// ---------------- zero flags (4 wv-groups x 16 WGs) ------------------------------
__global__ void zero_flags(int* __restrict__ f) { f[threadIdx.x] = 0; }

// ---------------- K1: xp = gather(emb_bf) @ WiT_bf^T + bi  (bf16 MFMA) ----------
__global__ __launch_bounds__(256) void k1_mfma(const int* __restrict__ words,
                                               const unsigned short* __restrict__ embb,
                                               const unsigned short* __restrict__ WiT,
                                               const float* __restrict__ bi,
                                               unsigned short* __restrict__ xp) {
    __shared__ short As[128 * 40];
    __shared__ short Bs[128 * 40];
    __shared__ int wrow[128];
    const int tid = threadIdx.x;
    const int bx = blockIdx.x;       // n-tile 0..15
    const int by = blockIdx.y;       // m-tile 0..255
    if (tid < 128) {
        int m = by * 128 + tid;
        wrow[tid] = words[(m & 63) * TT + (m >> 6)];
    }
    const int lane = tid & 63;
    const int wv = tid >> 6;
    const int wm = (wv >> 1) * 64, wn = (wv & 1) * 64;
    const int fr = lane & 15, fg = lane >> 4;
    f32x4 acc[4][4] = {};
    float bv[4];
    #pragma unroll
    for (int ni = 0; ni < 4; ++ni) bv[ni] = bi[bx * 128 + wn + ni * 16 + fr];
    const int r0 = tid >> 2, sg = tid & 3;
    const int r1 = r0 + 64;
    __syncthreads();     // wrow visible
    s16x8 a0, a1, b0, b1;
    a0 = *(const s16x8*)&embb[(size_t)wrow[r0] * EE + sg * 8];
    a1 = *(const s16x8*)&embb[(size_t)wrow[r1] * EE + sg * 8];
    b0 = *(const s16x8*)&WiT[(size_t)(bx * 128 + r0) * EE + sg * 8];
    b1 = *(const s16x8*)&WiT[(size_t)(bx * 128 + r1) * EE + sg * 8];
    for (int kt = 0; kt < 16; ++kt) {
        __syncthreads();
        *(s16x8*)&As[r0 * 40 + sg * 8] = a0;
        *(s16x8*)&As[r1 * 40 + sg * 8] = a1;
        *(s16x8*)&Bs[r0 * 40 + sg * 8] = b0;
        *(s16x8*)&Bs[r1 * 40 + sg * 8] = b1;
        __syncthreads();
        if (kt < 15) {
            const int k0 = (kt + 1) * 32;
            a0 = *(const s16x8*)&embb[(size_t)wrow[r0] * EE + k0 + sg * 8];
            a1 = *(const s16x8*)&embb[(size_t)wrow[r1] * EE + k0 + sg * 8];
            b0 = *(const s16x8*)&WiT[(size_t)(bx * 128 + r0) * EE + k0 + sg * 8];
            b1 = *(const s16x8*)&WiT[(size_t)(bx * 128 + r1) * EE + k0 + sg * 8];
        }
        s16x8 af[4], bf_[4];
        #pragma unroll
        for (int i = 0; i < 4; ++i) {
            af[i]  = *(const s16x8*)&As[(wm + i * 16 + fr) * 40 + fg * 8];
            bf_[i] = *(const s16x8*)&Bs[(wn + i * 16 + fr) * 40 + fg * 8];
        }
        #pragma unroll
        for (int mi = 0; mi < 4; ++mi)
            #pragma unroll
            for (int ni = 0; ni < 4; ++ni)
                acc[mi][ni] = __builtin_amdgcn_mfma_f32_16x16x32_bf16(
                    af[mi], bf_[ni], acc[mi][ni], 0, 0, 0);
        __syncthreads();
    }
    #pragma unroll
    for (int mi = 0; mi < 4; ++mi) {
        #pragma unroll
        for (int ni = 0; ni < 4; ++ni) {
            int n = bx * 128 + wn + ni * 16 + fr;
            #pragma unroll
            for (int r = 0; r < 4; ++r) {
                int m = by * 128 + wm + mi * 16 + fg * 4 + r;
                xp[(size_t)m * G4 + n] = f2bf(acc[mi][ni][r] + bv[ni]);
            }
        }
    }
}

// ---------------- K2: persistent LSTM recurrence (fan-in 16) ---------------------
// 16 WGs x 256 threads. WG wg owns units u0=wg*32..+32 (128 gate cols).
// Wave wv owns batches wv*16..+16. R8 protocol byte-for-byte: poll -> clustered
// cached h loads -> MFMA -> gates -> 4B atomic h stores -> vmcnt(0) -> publish
// -> xp prefetch. Chain fan-in: 16 producers / 16 flags (was 64/64).
// Wl row n (n = cg*16 + f2): gate=(n>>4>=4?2:0)+(f2>>3), uo=((n>>4)&3)*8+(f2&7)
// -> acc[cg] lane fr pairs r/f (cg<4) and g/o (cg>=4) via shfl_xor(8), as R8.
__global__ __launch_bounds__(256, 1) void k2_persistent(
        const unsigned short* __restrict__ WhT,  // [2048][512] bf16
        const unsigned short* __restrict__ xp,   // [T*B][2048] bf16
        const float* __restrict__ bh,            // [2048]
        unsigned short* __restrict__ hs,         // [T][B][H] bf16 (out)
        int* __restrict__ flags) {               // [4*16], zeroed
    extern __shared__ short Wl[];                // [128][520]
    const int wg = blockIdx.x;
    const int tid = threadIdx.x;
    const int lane = tid & 63, wv = tid >> 6;
    const int fr = lane & 15, fg = lane >> 4;
    const int u0 = wg * 32;
    // stage Wh slice (128 cols x 512 k)
    for (int i = tid; i < 128 * 64; i += 256) {
        int n = i >> 6, kc = i & 63;
        int cg = n >> 4, f2 = n & 15;
        int gate = ((cg >> 2) << 1) + (f2 >> 3);
        int uo = (cg & 3) * 8 + (f2 & 7);
        int gcol = gate * HH + u0 + uo;
        *(s16x8*)&Wl[n * 520 + kc * 8] = *(const s16x8*)&WhT[(size_t)gcol * HH + kc * 8];
    }
    // per-lane gate columns and biases (cg = 0..3)
    int col0[4], col1[4];
    float bh0[4], bh1[4];
    #pragma unroll
    for (int cg = 0; cg < 4; ++cg) {
        col0[cg] = (fr >> 3) * HH + u0 + cg * 8 + (fr & 7);        // r/f
        col1[cg] = (2 + (fr >> 3)) * HH + u0 + cg * 8 + (fr & 7);  // g/o
        bh0[cg] = bh[col0[cg]];
        bh1[cg] = bh[col1[cg]];
    }
    const int wb = wv * 16;                      // batch base of this wave
    float cst[4][4];
    #pragma unroll
    for (int cg = 0; cg < 4; ++cg)
        #pragma unroll
        for (int r = 0; r < 4; ++r) cst[cg][r] = 0.f;
    // prefetch xp for t=0
    unsigned short xq0[4][4], xq1[4][4];
    {
        const unsigned short* xrow = xp + ((size_t)(wb + fg * 4)) * G4;
        #pragma unroll
        for (int cg = 0; cg < 4; ++cg)
            #pragma unroll
            for (int r = 0; r < 4; ++r) {
                xq0[cg][r] = xrow[(size_t)r * G4 + col0[cg]];
                xq1[cg][r] = xrow[(size_t)r * G4 + col1[cg]];
            }
    }
    __syncthreads();                             // Wl ready
    for (int t = 0; t < TT; ++t) {
        f32x4 acc[8];
        #pragma unroll
        for (int cg = 0; cg < 8; ++cg) acc[cg] = (f32x4){0.f, 0.f, 0.f, 0.f};
        if (t > 0) {
            // poll the 16 wave-wv flags (one 64B line)
            while (1) {
                int v = __hip_atomic_load(&flags[wv * 16 + (lane & 15)], __ATOMIC_RELAXED,
                                          __HIP_MEMORY_SCOPE_AGENT);
                if (__all(v >= t)) break;
            }
            asm volatile("" ::: "memory");   // no load hoisting above the flag
            // cached coalesced load of h[t-1]: lane reads row (wb+fr), 16B @ fg*8+kt*32
            const s16x8* hrow = (const s16x8*)
                (hs + ((size_t)(t - 1) * BB + wb + fr) * HH + fg * 8);
            s16x8 a[16];
            #pragma unroll
            for (int kt = 0; kt < 16; ++kt) a[kt] = hrow[kt * 4];
            // pin: all 16 loads issued before any MFMA is scheduled
            __builtin_amdgcn_sched_barrier(0);
            #pragma unroll
            for (int kt = 0; kt < 16; ++kt) {
                #pragma unroll
                for (int cg = 0; cg < 8; ++cg) {
                    s16x8 b = *(const s16x8*)&Wl[(cg * 16 + fr) * 520 + kt * 32 + fg * 8];
                    acc[cg] = __builtin_amdgcn_mfma_f32_16x16x32_bf16(a[kt], b, acc[cg], 0, 0, 0);
                }
            }
        }
        // gates + state update + h stores; C layout row=fg*4+r (batch), col=fr
        #pragma unroll
        for (int cg = 0; cg < 4; ++cg) {
            #pragma unroll
            for (int r = 0; r < 4; ++r) {
                float g0 = acc[cg][r] + b2f(xq0[cg][r]) + bh0[cg];
                float g1 = acc[cg + 4][r] + b2f(xq1[cg][r]) + bh1[cg];
                float rv = g0, fv = __shfl_xor(g0, 8);
                float gv = g1, ov = __shfl_xor(g1, 8);
                float rt = 1.f / (1.f + __expf(-rv));
                float ft = 1.f / (1.f + __expf(-fv));
                float gt = tanhf(gv);
                float ot = 1.f / (1.f + __expf(-ov));
                cst[cg][r] = ft * cst[cg][r] + rt * gt;
                float h = ot * tanhf(cst[cg][r]);
                unsigned short hu = f2bf(h);      // valid for fr<8 (unit u0+cg*8+fr)
                unsigned short pu = (unsigned short)__shfl_xor((int)hu, 1);
                if (fr < 8 && (fr & 1) == 0) {
                    unsigned int packed = (unsigned)hu | ((unsigned)pu << 16);
                    unsigned int* dst = (unsigned int*)
                        (hs + ((size_t)t * BB + wb + fg * 4 + r) * HH + u0 + cg * 8 + fr);
                    __hip_atomic_store(dst, packed, __ATOMIC_RELAXED,
                                       __HIP_MEMORY_SCOPE_AGENT);
                }
            }
        }
        // drain own h stores to LLC, then publish this wave's flag
        asm volatile("s_waitcnt vmcnt(0)" ::: "memory");
        __hip_atomic_store(&flags[wv * 16 + wg], t + 1, __ATOMIC_RELAXED,
                           __HIP_MEMORY_SCOPE_AGENT);
        // prefetch xp for next step (in flight during next poll)
        {
            int tn = (t + 1 < TT) ? (t + 1) : t;
            const unsigned short* xrow = xp + ((size_t)tn * BB + wb + fg * 4) * G4;
            #pragma unroll
            for (int cg = 0; cg < 4; ++cg)
                #pragma unroll
                for (int r = 0; r < 4; ++r) {
                    xq0[cg][r] = xrow[(size_t)r * G4 + col0[cg]];
                    xq1[cg][r] = xrow[(size_t)r * G4 + col1[cg]];
                }
        }
    }
}

// ---------------- K3: final_hidden = h @ W_lstm + b_lstm -------------------------
__global__ __launch_bounds__(512) void k3_fh(const unsigned short* __restrict__ hs,
                                             const float* __restrict__ Wl,
                                             const float* __restrict__ bl,
                                             float* __restrict__ fh) {
    const int b = blockIdx.x;
    const int j = threadIdx.x;
    __shared__ float hl[512];
    hl[j] = b2f(hs[((size_t)(TT - 1) * BB + b) * HH + j]);
    __syncthreads();
    float acc = bl[j];
    #pragma unroll 8
    for (int k = 0; k < HH; ++k) acc += hl[k] * Wl[(size_t)k * HH + j];
    fh[(size_t)b * HH + j] = acc;
}

// ---------------- K4: score -> softmax -> att -> output head ---------------------
__global__ __launch_bounds__(256) void k4_att(const unsigned short* __restrict__ hs,
                                              const float* __restrict__ fh,
                                              const float* __restrict__ Wa,
                                              const float* __restrict__ ba,
                                              float* __restrict__ out) {
    const int b = blockIdx.x;
    const int tid = threadIdx.x;
    const int lane = tid & 63, w = tid >> 6;
    __shared__ float scores[512];
    __shared__ float attl[512];
    __shared__ float red[8];
    float fr[8];
    *(float4*)&fr[0] = *(const float4*)&fh[(size_t)b * HH + lane * 8];
    *(float4*)&fr[4] = *(const float4*)&fh[(size_t)b * HH + lane * 8 + 4];
    for (int t = w; t < TT; t += 4) {
        const unsigned short* hrow = hs + ((size_t)t * BB + b) * HH + lane * 8;
        u16x8 hv = *(const u16x8*)hrow;
        float v = 0.f;
        #pragma unroll
        for (int i = 0; i < 8; ++i) v += b2f(hv[i]) * fr[i];
        #pragma unroll
        for (int o = 32; o; o >>= 1) v += __shfl_xor(v, o);
        if (lane == 0) scores[t] = v;
    }
    __syncthreads();
    float s0 = scores[tid], s1 = scores[tid + 256];
    float m = fmaxf(s0, s1);
    #pragma unroll
    for (int o = 32; o; o >>= 1) m = fmaxf(m, __shfl_xor(m, o));
    if (lane == 0) red[w] = m;
    __syncthreads();
    m = fmaxf(fmaxf(red[0], red[1]), fmaxf(red[2], red[3]));
    float e0 = __expf(s0 - m), e1 = __expf(s1 - m);
    float s = e0 + e1;
    #pragma unroll
    for (int o = 32; o; o >>= 1) s += __shfl_xor(s, o);
    if (lane == 0) red[4 + w] = s;
    __syncthreads();
    s = red[4] + red[5] + red[6] + red[7];
    float inv = 1.f / s;
    scores[tid] = e0 * inv;
    scores[tid + 256] = e1 * inv;
    __syncthreads();
    float a0 = 0.f, a1 = 0.f;
    for (int t = 0; t < TT; ++t) {
        float d = scores[t];
        const unsigned short* hrow = hs + ((size_t)t * BB + b) * HH;
        a0 += d * b2f(hrow[tid]);
        a1 += d * b2f(hrow[tid + 256]);
    }
    attl[tid] = a0; attl[tid + 256] = a1;
    const unsigned short* hlast = hs + ((size_t)(TT - 1) * BB + b) * HH;
    out[64 + (size_t)b * HH + tid] = b2f(hlast[tid]);
    out[64 + (size_t)b * HH + tid + 256] = b2f(hlast[tid + 256]);
    __syncthreads();
    float p = fh[(size_t)b * HH + tid] * Wa[tid]
            + fh[(size_t)b * HH + tid + 256] * Wa[tid + 256]
            + attl[tid] * Wa[512 + tid]
            + attl[tid + 256] * Wa[768 + tid];
    #pragma unroll
    for (int o = 32; o; o >>= 1) p += __shfl_xor(p, o);
    if (lane == 0) red[w] = p;
    __syncthreads();
    if (tid == 0) {
        float v = red[0] + red[1] + red[2] + red[3] + ba[0];
        out[b] = 1.f / (1.f + __expf(-v));
    }
}

extern "C" void kernel_launch(void* const* d_in, const int* in_sizes, int n_in,
                              void* d_out, int out_size, void* d_ws, size_t ws_size,
                              hipStream_t stream) {
    const int*   words = (const int*)d_in[0];
    const float* emb   = (const float*)d_in[1];
    const float* Wi    = (const float*)d_in[2];
    const float* bi    = (const float*)d_in[3];
    const float* Wh    = (const float*)d_in[4];
    const float* bh    = (const float*)d_in[5];
    const float* Wl    = (const float*)d_in[6];
    const float* blst  = (const float*)d_in[7];
    const float* Wa    = (const float*)d_in[8];
    const float* ba    = (const float*)d_in[9];
    float* out = (float*)d_out;

    char* ws = (char*)d_ws;
    size_t off = 0;
    unsigned short* emb_bf = (unsigned short*)(ws + off); off += (size_t)VV * EE * 2;      // 32.8 MB
    unsigned short* WiT    = (unsigned short*)(ws + off); off += (size_t)G4 * HH * 2;      // 2 MB
    unsigned short* WhT    = (unsigned short*)(ws + off); off += (size_t)G4 * HH * 2;      // 2 MB
    unsigned short* xp     = (unsigned short*)(ws + off); off += (size_t)TT * BB * G4 * 2; // 128 MB
    unsigned short* hs     = (unsigned short*)(ws + off); off += (size_t)TT * BB * HH * 2; // 32 MB
    float* fh    = (float*)(ws + off); off += (size_t)BB * HH * 4;
    int*   flags = (int*)(ws + off);   off += 4 * NWG * sizeof(int);
    (void)ws_size; (void)in_sizes; (void)n_in; (void)out_size;

    c_bf16<<<(VV * EE / 4 + 255) / 256, 256, 0, stream>>>(emb, emb_bf, VV * EE / 4);
    c_wT<<<dim3(64, 16), 256, 0, stream>>>(Wi, WiT);
    c_wT<<<dim3(64, 16), 256, 0, stream>>>(Wh, WhT);
    zero_flags<<<1, 4 * NWG, 0, stream>>>(flags);
    k1_mfma<<<dim3(16, 256), 256, 0, stream>>>(words, emb_bf, WiT, bi, xp);
    k2_persistent<<<NWG, 256, 128 * 520 * sizeof(short), stream>>>(WhT, xp, bh, hs, flags);
    k3_fh<<<64, 512, 0, stream>>>(hs, Wl, blst, fh);
    k4_att<<<64, 256, 0, stream>>>(hs, fh, Wa, ba, out);
}

// Round 14
// 2328.118 us; speedup vs baseline: 2.1064x; 2.1064x over previous
//
#include <hip/hip_runtime.h>
#include <hip/hip_bf16.h>

// Problem constants
#define BB 64     // batch
#define TT 512    // seq len
#define EE 512    // embed dim
#define HH 512    // hidden
#define G4 2048   // 4*H
#define VV 32000  // vocab
#define NWG 64    // workgroups in persistent recurrence kernel
#define FPAD 16   // flag padding: 16 ints = 64B = one LLC line per flag

typedef float f32x4 __attribute__((ext_vector_type(4)));
typedef short s16x8 __attribute__((ext_vector_type(8)));
typedef unsigned short u16x8 __attribute__((ext_vector_type(8)));

__device__ __forceinline__ unsigned short f2bf(float x) {
    __hip_bfloat16 h = __float2bfloat16(x);
    return *(unsigned short*)&h;
}
__device__ __forceinline__ float b2f(unsigned short u) {
    return __uint_as_float(((unsigned)u) << 16);
}

// ---------------- C0: fp32 -> bf16 flat convert (emb) ---------------------------
__global__ __launch_bounds__(256) void c_bf16(const float* __restrict__ in,
                                              unsigned short* __restrict__ out, int n4) {
    int i = blockIdx.x * 256 + threadIdx.x;
    if (i < n4) {
        float4 v = ((const float4*)in)[i];
        ushort4 o;
        o.x = f2bf(v.x); o.y = f2bf(v.y); o.z = f2bf(v.z); o.w = f2bf(v.w);
        ((ushort4*)out)[i] = o;
    }
}

// ---------------- C1: transpose+convert [512][2048] fp32 -> [2048][512] bf16 ----
__global__ __launch_bounds__(256) void c_wT(const float* __restrict__ in,
                                            unsigned short* __restrict__ out) {
    __shared__ float tile[32][33];
    int gx = blockIdx.x * 32;           // col dim (2048)
    int ky = blockIdx.y * 32;           // row dim (512)
    int tx = threadIdx.x & 31, ty = threadIdx.x >> 5;   // 32 x 8
    #pragma unroll
    for (int i = 0; i < 32; i += 8)
        tile[ty + i][tx] = in[(size_t)(ky + ty + i) * G4 + gx + tx];
    __syncthreads();
    #pragma unroll
    for (int i = 0; i < 32; i += 8)
        out[(size_t)(gx + ty + i) * HH + ky + tx] = f2bf(tile[tx][ty + i]);
}

// ---------------- zero flags (4 wv-groups x 64 WGs x 16-int pad) -----------------
__global__ __launch_bounds__(256) void zero_flags(int* __restrict__ f) {
    f[blockIdx.x * 256 + threadIdx.x] = 0;
}

// ---------------- K1: xp = gather(emb_bf) @ WiT_bf^T + bi  (bf16 MFMA) ----------
__global__ __launch_bounds__(256) void k1_mfma(const int* __restrict__ words,
                                               const unsigned short* __restrict__ embb,
                                               const unsigned short* __restrict__ WiT,
                                               const float* __restrict__ bi,
                                               unsigned short* __restrict__ xp) {
    __shared__ short As[128 * 40];
    __shared__ short Bs[128 * 40];
    __shared__ int wrow[128];
    const int tid = threadIdx.x;
    const int bx = blockIdx.x;       // n-tile 0..15
    const int by = blockIdx.y;       // m-tile 0..255
    if (tid < 128) {
        int m = by * 128 + tid;
        wrow[tid] = words[(m & 63) * TT + (m >> 6)];
    }
    const int lane = tid & 63;
    const int wv = tid >> 6;
    const int wm = (wv >> 1) * 64, wn = (wv & 1) * 64;
    const int fr = lane & 15, fg = lane >> 4;
    f32x4 acc[4][4] = {};
    float bv[4];
    #pragma unroll
    for (int ni = 0; ni < 4; ++ni) bv[ni] = bi[bx * 128 + wn + ni * 16 + fr];
    const int r0 = tid >> 2, sg = tid & 3;
    const int r1 = r0 + 64;
    __syncthreads();     // wrow visible
    s16x8 a0, a1, b0, b1;
    a0 = *(const s16x8*)&embb[(size_t)wrow[r0] * EE + sg * 8];
    a1 = *(const s16x8*)&embb[(size_t)wrow[r1] * EE + sg * 8];
    b0 = *(const s16x8*)&WiT[(size_t)(bx * 128 + r0) * EE + sg * 8];
    b1 = *(const s16x8*)&WiT[(size_t)(bx * 128 + r1) * EE + sg * 8];
    for (int kt = 0; kt < 16; ++kt) {
        __syncthreads();
        *(s16x8*)&As[r0 * 40 + sg * 8] = a0;
        *(s16x8*)&As[r1 * 40 + sg * 8] = a1;
        *(s16x8*)&Bs[r0 * 40 + sg * 8] = b0;
        *(s16x8*)&Bs[r1 * 40 + sg * 8] = b1;
        __syncthreads();
        if (kt < 15) {
            const int k0 = (kt + 1) * 32;
            a0 = *(const s16x8*)&embb[(size_t)wrow[r0] * EE + k0 + sg * 8];
            a1 = *(const s16x8*)&embb[(size_t)wrow[r1] * EE + k0 + sg * 8];
            b0 = *(const s16x8*)&WiT[(size_t)(bx * 128 + r0) * EE + k0 + sg * 8];
            b1 = *(const s16x8*)&WiT[(size_t)(bx * 128 + r1) * EE + k0 + sg * 8];
        }
        s16x8 af[4], bf_[4];
        #pragma unroll
        for (int i = 0; i < 4; ++i) {
            af[i]  = *(const s16x8*)&As[(wm + i * 16 + fr) * 40 + fg * 8];
            bf_[i] = *(const s16x8*)&Bs[(wn + i * 16 + fr) * 40 + fg * 8];
        }
        #pragma unroll
        for (int mi = 0; mi < 4; ++mi)
            #pragma unroll
            for (int ni = 0; ni < 4; ++ni)
                acc[mi][ni] = __builtin_amdgcn_mfma_f32_16x16x32_bf16(
                    af[mi], bf_[ni], acc[mi][ni], 0, 0, 0);
        __syncthreads();
    }
    #pragma unroll
    for (int mi = 0; mi < 4; ++mi) {
        #pragma unroll
        for (int ni = 0; ni < 4; ++ni) {
            int n = bx * 128 + wn + ni * 16 + fr;
            #pragma unroll
            for (int r = 0; r < 4; ++r) {
                int m = by * 128 + wm + mi * 16 + fg * 4 + r;
                xp[(size_t)m * G4 + n] = f2bf(acc[mi][ni][r] + bv[ni]);
            }
        }
    }
}

// ---------------- K2: persistent LSTM recurrence (R8 + line-padded flags) --------
// Exact R8 structure (2561us = best known). ONE change: each per-wave flag gets
// its own 64B LLC line (stride FPAD=16 ints). In R8 all 256 flags shared 4 lines:
// 64 producers/chain stored into the same lines the 256 polling waves hammer ->
// per-line serialization at the coherence point inflated publish visibility and
// poll RTT. Disjoint lines remove that contention.
__global__ __launch_bounds__(256) void k2_persistent(
        const unsigned short* __restrict__ WhT,  // [2048][512] bf16
        const unsigned short* __restrict__ xp,   // [T*B][2048] bf16
        const float* __restrict__ bh,            // [2048]
        unsigned short* __restrict__ hs,         // [T][B][H] bf16 (out)
        int* __restrict__ flags) {               // [4*64*FPAD], zeroed
    __shared__ short Wl[32 * 520];               // [n 0..31][k 0..511] pad 8
    const int wg = blockIdx.x;
    const int tid = threadIdx.x;
    const int lane = tid & 63, wv = tid >> 6;
    const int fr = lane & 15, fg = lane >> 4;
    const int u0 = wg * 8;
    // stage Wh slice: row n -> global col (n>>3)*512 + u0 + (n&7)
    for (int i = tid; i < 32 * 64; i += 256) {
        int n = i >> 6, kc = i & 63;
        int col = (n >> 3) * HH + u0 + (n & 7);
        *(s16x8*)&Wl[n * 520 + kc * 8] = *(const s16x8*)&WhT[(size_t)col * HH + kc * 8];
    }
    const int col0 = ((fr >> 3) ? HH : 0) + u0 + (fr & 7);          // tile0: r/f
    const int col1 = ((fr >> 3) ? 3 * HH : 2 * HH) + u0 + (fr & 7); // tile1: g/o
    const float bh0 = bh[col0], bh1 = bh[col1];
    const int wb = wv * 16;                      // batch base of this wave
    float cst[4] = {0.f, 0.f, 0.f, 0.f};
    // prefetch xp for t=0
    unsigned short xq0[4], xq1[4];
    {
        const unsigned short* xrow = xp + ((size_t)(wb + fg * 4)) * G4;
        #pragma unroll
        for (int r = 0; r < 4; ++r) {
            xq0[r] = xrow[(size_t)r * G4 + col0];
            xq1[r] = xrow[(size_t)r * G4 + col1];
        }
    }
    __syncthreads();                             // Wl ready
    for (int t = 0; t < TT; ++t) {
        f32x4 acc0 = {0.f, 0.f, 0.f, 0.f}, acc1 = {0.f, 0.f, 0.f, 0.f};
        if (t > 0) {
            // wait for wave-wv of every WG to have published h[t-1]
            while (1) {
                int v = __hip_atomic_load(&flags[(wv * 64 + lane) * FPAD],
                                          __ATOMIC_RELAXED, __HIP_MEMORY_SCOPE_AGENT);
                if (__all(v >= t)) break;
            }
            asm volatile("" ::: "memory");   // no load hoisting above the flag
            // cached coalesced load of h[t-1]: lane reads row (wb+fr), 16B @ fg*8+kt*32
            const s16x8* hrow = (const s16x8*)
                (hs + ((size_t)(t - 1) * BB + wb + fr) * HH + fg * 8);
            s16x8 a[16];
            #pragma unroll
            for (int kt = 0; kt < 16; ++kt) a[kt] = hrow[kt * 4];
            // pin: all 16 loads issued before any MFMA is scheduled
            __builtin_amdgcn_sched_barrier(0);
            #pragma unroll
            for (int kt = 0; kt < 16; ++kt) {
                s16x8 b0 = *(const s16x8*)&Wl[fr * 520 + kt * 32 + fg * 8];
                s16x8 b1 = *(const s16x8*)&Wl[(16 + fr) * 520 + kt * 32 + fg * 8];
                acc0 = __builtin_amdgcn_mfma_f32_16x16x32_bf16(a[kt], b0, acc0, 0, 0, 0);
                acc1 = __builtin_amdgcn_mfma_f32_16x16x32_bf16(a[kt], b1, acc1, 0, 0, 0);
            }
        }
        // gates: acc + xp + bh; C layout row=fg*4+r (batch), col=fr
        float g0[4], g1[4];
        #pragma unroll
        for (int r = 0; r < 4; ++r) {
            g0[r] = acc0[r] + b2f(xq0[r]) + bh0;
            g1[r] = acc1[r] + b2f(xq1[r]) + bh1;
        }
        #pragma unroll
        for (int r = 0; r < 4; ++r) {
            float rv = g0[r], fv = __shfl_xor(g0[r], 8);
            float gv = g1[r], ov = __shfl_xor(g1[r], 8);
            float rt = 1.f / (1.f + __expf(-rv));
            float ft = 1.f / (1.f + __expf(-fv));
            float gt = tanhf(gv);
            float ot = 1.f / (1.f + __expf(-ov));
            cst[r] = ft * cst[r] + rt * gt;
            float h = ot * tanhf(cst[r]);
            unsigned short hu = f2bf(h);
            unsigned short pu = (unsigned short)__shfl_xor((int)hu, 1);
            if (fr < 8 && (fr & 1) == 0) {
                unsigned int packed = (unsigned)hu | ((unsigned)pu << 16);
                unsigned int* dst = (unsigned int*)
                    (hs + ((size_t)t * BB + wb + fg * 4 + r) * HH + u0 + fr);
                __hip_atomic_store(dst, packed, __ATOMIC_RELAXED,
                                   __HIP_MEMORY_SCOPE_AGENT);
            }
        }
        // drain own h stores to LLC, then publish this wave's flag
        asm volatile("s_waitcnt vmcnt(0)" ::: "memory");
        __hip_atomic_store(&flags[(wv * 64 + wg) * FPAD], t + 1, __ATOMIC_RELAXED,
                           __HIP_MEMORY_SCOPE_AGENT);
        // prefetch xp for next step (in flight during next poll)
        {
            int tn = (t + 1 < TT) ? (t + 1) : t;
            const unsigned short* xrow = xp + ((size_t)tn * BB + wb + fg * 4) * G4;
            #pragma unroll
            for (int r = 0; r < 4; ++r) {
                xq0[r] = xrow[(size_t)r * G4 + col0];
                xq1[r] = xrow[(size_t)r * G4 + col1];
            }
        }
    }
}

// ---------------- K3: final_hidden = h @ W_lstm + b_lstm -------------------------
__global__ __launch_bounds__(512) void k3_fh(const unsigned short* __restrict__ hs,
                                             const float* __restrict__ Wl,
                                             const float* __restrict__ bl,
                                             float* __restrict__ fh) {
    const int b = blockIdx.x;
    const int j = threadIdx.x;
    __shared__ float hl[512];
    hl[j] = b2f(hs[((size_t)(TT - 1) * BB + b) * HH + j]);
    __syncthreads();
    float acc = bl[j];
    #pragma unroll 8
    for (int k = 0; k < HH; ++k) acc += hl[k] * Wl[(size_t)k * HH + j];
    fh[(size_t)b * HH + j] = acc;
}

// ---------------- K4: score -> softmax -> att -> output head ---------------------
__global__ __launch_bounds__(256) void k4_att(const unsigned short* __restrict__ hs,
                                              const float* __restrict__ fh,
                                              const float* __restrict__ Wa,
                                              const float* __restrict__ ba,
                                              float* __restrict__ out) {
    const int b = blockIdx.x;
    const int tid = threadIdx.x;
    const int lane = tid & 63, w = tid >> 6;
    __shared__ float scores[512];
    __shared__ float attl[512];
    __shared__ float red[8];
    float fr[8];
    *(float4*)&fr[0] = *(const float4*)&fh[(size_t)b * HH + lane * 8];
    *(float4*)&fr[4] = *(const float4*)&fh[(size_t)b * HH + lane * 8 + 4];
    for (int t = w; t < TT; t += 4) {
        const unsigned short* hrow = hs + ((size_t)t * BB + b) * HH + lane * 8;
        u16x8 hv = *(const u16x8*)hrow;
        float v = 0.f;
        #pragma unroll
        for (int i = 0; i < 8; ++i) v += b2f(hv[i]) * fr[i];
        #pragma unroll
        for (int o = 32; o; o >>= 1) v += __shfl_xor(v, o);
        if (lane == 0) scores[t] = v;
    }
    __syncthreads();
    float s0 = scores[tid], s1 = scores[tid + 256];
    float m = fmaxf(s0, s1);
    #pragma unroll
    for (int o = 32; o; o >>= 1) m = fmaxf(m, __shfl_xor(m, o));
    if (lane == 0) red[w] = m;
    __syncthreads();
    m = fmaxf(fmaxf(red[0], red[1]), fmaxf(red[2], red[3]));
    float e0 = __expf(s0 - m), e1 = __expf(s1 - m);
    float s = e0 + e1;
    #pragma unroll
    for (int o = 32; o; o >>= 1) s += __shfl_xor(s, o);
    if (lane == 0) red[4 + w] = s;
    __syncthreads();
    s = red[4] + red[5] + red[6] + red[7];
    float inv = 1.f / s;
    scores[tid] = e0 * inv;
    scores[tid + 256] = e1 * inv;
    __syncthreads();
    float a0 = 0.f, a1 = 0.f;
    for (int t = 0; t < TT; ++t) {
        float d = scores[t];
        const unsigned short* hrow = hs + ((size_t)t * BB + b) * HH;
        a0 += d * b2f(hrow[tid]);
        a1 += d * b2f(hrow[tid + 256]);
    }
    attl[tid] = a0; attl[tid + 256] = a1;
    const unsigned short* hlast = hs + ((size_t)(TT - 1) * BB + b) * HH;
    out[64 + (size_t)b * HH + tid] = b2f(hlast[tid]);
    out[64 + (size_t)b * HH + tid + 256] = b2f(hlast[tid + 256]);
    __syncthreads();
    float p = fh[(size_t)b * HH + tid] * Wa[tid]
            + fh[(size_t)b * HH + tid + 256] * Wa[tid + 256]
            + attl[tid] * Wa[512 + tid]
            + attl[tid + 256] * Wa[768 + tid];
    #pragma unroll
    for (int o = 32; o; o >>= 1) p += __shfl_xor(p, o);
    if (lane == 0) red[w] = p;
    __syncthreads();
    if (tid == 0) {
        float v = red[0] + red[1] + red[2] + red[3] + ba[0];
        out[b] = 1.f / (1.f + __expf(-v));
    }
}

extern "C" void kernel_launch(void* const* d_in, const int* in_sizes, int n_in,
                              void* d_out, int out_size, void* d_ws, size_t ws_size,
                              hipStream_t stream) {
    const int*   words = (const int*)d_in[0];
    const float* emb   = (const float*)d_in[1];
    const float* Wi    = (const float*)d_in[2];
    const float* bi    = (const float*)d_in[3];
    const float* Wh    = (const float*)d_in[4];
    const float* bh    = (const float*)d_in[5];
    const float* Wl    = (const float*)d_in[6];
    const float* blst  = (const float*)d_in[7];
    const float* Wa    = (const float*)d_in[8];
    const float* ba    = (const float*)d_in[9];
    float* out = (float*)d_out;

    char* ws = (char*)d_ws;
    size_t off = 0;
    unsigned short* emb_bf = (unsigned short*)(ws + off); off += (size_t)VV * EE * 2;      // 32.8 MB
    unsigned short* WiT    = (unsigned short*)(ws + off); off += (size_t)G4 * HH * 2;      // 2 MB
    unsigned short* WhT    = (unsigned short*)(ws + off); off += (size_t)G4 * HH * 2;      // 2 MB
    unsigned short* xp     = (unsigned short*)(ws + off); off += (size_t)TT * BB * G4 * 2; // 128 MB
    unsigned short* hs     = (unsigned short*)(ws + off); off += (size_t)TT * BB * HH * 2; // 32 MB
    float* fh    = (float*)(ws + off); off += (size_t)BB * HH * 4;
    int*   flags = (int*)(ws + off);   off += 4 * NWG * FPAD * sizeof(int);  // 16 KB
    (void)ws_size; (void)in_sizes; (void)n_in; (void)out_size;

    c_bf16<<<(VV * EE / 4 + 255) / 256, 256, 0, stream>>>(emb, emb_bf, VV * EE / 4);
    c_wT<<<dim3(64, 16), 256, 0, stream>>>(Wi, WiT);
    c_wT<<<dim3(64, 16), 256, 0, stream>>>(Wh, WhT);
    zero_flags<<<(4 * NWG * FPAD) / 256, 256, 0, stream>>>(flags);
    k1_mfma<<<dim3(16, 256), 256, 0, stream>>>(words, emb_bf, WiT, bi, xp);
    k2_persistent<<<NWG, 256, 0, stream>>>(WhT, xp, bh, hs, flags);
    k3_fh<<<64, 512, 0, stream>>>(hs, Wl, blst, fh);
    k4_att<<<64, 256, 0, stream>>>(hs, fh, Wa, ba, out);
}